// Round 10
// baseline (216.936 us; speedup 1.0000x reference)
//
#include <hip/hip_runtime.h>

#define NTOK 2048
#define NB 4
#define NH 8
#define DH 128

typedef __bf16 bf16x8 __attribute__((ext_vector_type(8)));
typedef unsigned short u16x8 __attribute__((ext_vector_type(8)));
typedef float f32x4 __attribute__((ext_vector_type(4)));
typedef float f32x16 __attribute__((ext_vector_type(16)));
typedef unsigned int u32x4 __attribute__((ext_vector_type(4)));

__device__ __forceinline__ f32x4 mfma16(bf16x8 a, bf16x8 b, f32x4 c) {
  return __builtin_amdgcn_mfma_f32_16x16x32_bf16(a, b, c, 0, 0, 0);
}
__device__ __forceinline__ f32x16 mfma32(bf16x8 a, bf16x8 b, f32x16 c) {
  return __builtin_amdgcn_mfma_f32_32x32x16_bf16(a, b, c, 0, 0, 0);
}
__device__ __forceinline__ bf16x8 ldb(const unsigned short* p) {
  return __builtin_bit_cast(bf16x8, *(const u16x8*)p);
}
__device__ __forceinline__ bf16x8 ldsb(const char* p) {
  return __builtin_bit_cast(bf16x8, *(const u16x8*)p);
}
__device__ __forceinline__ unsigned short f2bf(float f) {
  unsigned int u = __builtin_bit_cast(unsigned int, f);
  u += 0x7fffu + ((u >> 16) & 1u);
  return (unsigned short)(u >> 16);
}
__device__ __forceinline__ unsigned int cvtpk(float lo, float hi) {
  unsigned int r;
  asm("v_cvt_pk_bf16_f32 %0, %1, %2" : "=v"(r) : "v"(lo), "v"(hi));
  return r;
}
#if __has_builtin(__builtin_amdgcn_exp2f)
__device__ __forceinline__ float exp2a(float x) { return __builtin_amdgcn_exp2f(x); }
#else
__device__ __forceinline__ float exp2a(float x) { return __expf(x * 0.6931471805599453f); }
#endif
// async global->LDS, 16B per lane; LDS dest = wave-uniform base + lane*16
#define GLL(gsrc, ldst) __builtin_amdgcn_global_load_lds(                      \
    (const __attribute__((address_space(1))) void*)(gsrc),                     \
    (__attribute__((address_space(3))) void*)(ldst), 16, 0, 0)
#define WAITVM_(N) asm volatile("s_waitcnt vmcnt(" #N ")" ::: "memory")
#define WAITVM(N) WAITVM_(N)
#define SFENCE() asm volatile("" ::: "memory")

// flag: 0 = int32, 1 = uint8, 2 = float32 (int-compare works for 0/1.0f too)
__device__ __forceinline__ bool mask_at(const void* p, int flag, int idx) {
  if (flag == 1) return ((const unsigned char*)p)[idx] != 0;
  return ((const int*)p)[idx] != 0;
}

// ---- prep: detect mask dtype + cvt x to bf16 + LDS-tiled weight transpose ----
__global__ __launch_bounds__(256) void k_prep(
    const float* __restrict__ x, const float* __restrict__ Wq,
    const float* __restrict__ Wk, const float* __restrict__ Wv,
    const float* __restrict__ Wo, const unsigned int* __restrict__ amdw,
    unsigned short* __restrict__ xb, unsigned short* __restrict__ wqt,
    unsigned short* __restrict__ wkt, unsigned short* __restrict__ wvt,
    unsigned short* __restrict__ wot, int* __restrict__ flag) {
  int bid = blockIdx.x, tid = threadIdx.x;
  if (bid == 0) {
    __shared__ int su8, sf32;
    if (tid == 0) { su8 = 0; sf32 = 0; }
    __syncthreads();
    const uint4* dw4 = (const uint4*)amdw;
    int lu8 = 0, lf32 = 0;
#pragma unroll
    for (int j = 0; j < 16; j++) {
      uint4 q = dw4[tid + j * 256];
      unsigned int vv[4] = {q.x, q.y, q.z, q.w};
#pragma unroll
      for (int e = 0; e < 4; e++) {
        unsigned int v = vv[e];
        if (v == 0x3f800000u) lf32 = 1;
        else if (v != 0u && v != 1u) lu8 = 1;
      }
    }
    if (lu8) atomicOr(&su8, 1);
    if (lf32) atomicOr(&sf32, 1);
    __syncthreads();
    if (tid == 0) *flag = sf32 ? 2 : (su8 ? 1 : 0);
    return;
  }
  if (bid < 513) {
    int base = (bid - 1) * 2048 + tid * 8;
    const float4* xf = (const float4*)(x + base);
    float4 a = xf[0], b = xf[1];
    u16x8 o;
    o[0] = f2bf(a.x); o[1] = f2bf(a.y); o[2] = f2bf(a.z); o[3] = f2bf(a.w);
    o[4] = f2bf(b.x); o[5] = f2bf(b.y); o[6] = f2bf(b.z); o[7] = f2bf(b.w);
    *(u16x8*)(xb + base) = o;
    return;
  }
  __shared__ float tile[64][65];
  int tb = bid - 513;
  int msel = tb >> 5, tt = tb & 31;
  const float* w; unsigned short* wt; int R, C;
  if (msel == 0)      { w = Wq; wt = wqt; R = 128;  C = 1024; }
  else if (msel == 1) { w = Wk; wt = wkt; R = 128;  C = 1024; }
  else if (msel == 2) { w = Wv; wt = wvt; R = 128;  C = 1024; }
  else                { w = Wo; wt = wot; R = 1024; C = 128; }
  int nrt = R >> 6;
  int rt = (tt % nrt) << 6, ct = (tt / nrt) << 6;
  {
    int cl = tid & 63, rg = tid >> 6;
#pragma unroll
    for (int j = 0; j < 16; j++) {
      int row = rg * 16 + j;
      tile[row][cl] = w[(size_t)(rt + row) * C + ct + cl];
    }
  }
  __syncthreads();
  {
    int rl = tid & 63, cg = tid >> 6;
#pragma unroll
    for (int j = 0; j < 16; j++) {
      int col = cg * 16 + j;
      wt[(size_t)(ct + col) * R + rt + rl] = f2bf(tile[rl][col]);
    }
  }
}

// ---- fused QKV projection (LDS-staged weights) + mask bit-pack (word/thread) ----
__global__ __launch_bounds__(256) void k_qkv_pack(
    const unsigned short* __restrict__ xb, const unsigned short* __restrict__ wqt,
    const unsigned short* __restrict__ wkt, const unsigned short* __restrict__ wvt,
    unsigned short* __restrict__ qb, unsigned short* __restrict__ kbuf,
    unsigned short* __restrict__ vtb, const void* __restrict__ am,
    const int* __restrict__ flagp, unsigned int* __restrict__ bits) {
  __shared__ char smem[49152];
  int bid = blockIdx.x;
  int lane = threadIdx.x & 63, w = threadIdx.x >> 6;
  if (bid >= 3072) {
    int flag = *flagp;
    size_t ebase = (size_t)(bid - 3072) * 8192 + (size_t)threadIdx.x * 32;
    unsigned int word = 0;
    if (flag == 1) {
      const uint4* p4 = (const uint4*)((const unsigned char*)am + ebase);
      uint4 q0 = p4[0], q1 = p4[1];
      unsigned int dw[8] = {q0.x, q0.y, q0.z, q0.w, q1.x, q1.y, q1.z, q1.w};
#pragma unroll
      for (int d = 0; d < 8; d++) {
        unsigned int v = dw[d];
        if (v & 0x000000FFu) word |= 1u << (d * 4 + 0);
        if (v & 0x0000FF00u) word |= 1u << (d * 4 + 1);
        if (v & 0x00FF0000u) word |= 1u << (d * 4 + 2);
        if (v & 0xFF000000u) word |= 1u << (d * 4 + 3);
      }
    } else {
      const uint4* p4 = (const uint4*)((const int*)am + ebase);
#pragma unroll
      for (int k = 0; k < 8; k++) {
        uint4 q = p4[k];
        if (q.x) word |= 1u << (k * 4 + 0);
        if (q.y) word |= 1u << (k * 4 + 1);
        if (q.z) word |= 1u << (k * 4 + 2);
        if (q.w) word |= 1u << (k * 4 + 3);
      }
    }
    bits[ebase >> 5] = word;
    return;
  }
  int which = bid >> 10;
  int rem = bid & 1023;
  int bx = rem & 127, by = rem >> 7;
  const unsigned short* wt = which == 0 ? wqt : (which == 1 ? wkt : wvt);
  int lo = lane & 15, g = lane >> 4;
  int rbase = bx * 64 + w * 16;
  int colb = by * 128;
  char* wl = smem;
  {
    const char* Wg = (const char*)(wt + (size_t)colb * 128);
#pragma unroll
    for (int s = 0; s < 8; s++) {
      int a = s * 4096 + w * 1024 + lane * 16;
      int r = a >> 8;
      int cb = (a & 255) ^ ((r & 7) << 4);
      GLL(Wg + r * 256 + cb, wl + s * 4096 + w * 1024);
    }
  }
  bf16x8 af[4];
  const unsigned short* xrow = xb + (size_t)(rbase + lo) * 128 + g * 8;
#pragma unroll
  for (int s = 0; s < 4; s++) af[s] = ldb(xrow + 32 * s);
  __syncthreads();
  f32x4 acc[8] = {};
  int xw = (lo & 7) << 4;
#pragma unroll
  for (int c = 0; c < 8; c++) {
    const char* wrow = wl + (c * 16 + lo) * 256;
#pragma unroll
    for (int s = 0; s < 4; s++)
      acc[c] = mfma16(af[s], ldsb(wrow + ((64 * s + 16 * g) ^ xw)), acc[c]);
  }
  if (which != 2) {
    float sc = (which == 0) ? 0.12751743f : 1.0f;   // log2(e)/sqrt(128)
#pragma unroll
    for (int c = 0; c < 8; c++) {
#pragma unroll
      for (int r = 0; r < 4; r++) {
        int row = rbase + 4 * g + r;
        int col = colb + c * 16 + lo;
        int b = row >> 11, n = row & (NTOK - 1);
        int h = col >> 7, d = col & 127;
        unsigned short val = f2bf(acc[c][r] * sc);
        size_t bh = (size_t)(b * NH + h);
        if (which == 0) qb[(bh * NTOK + n) * DH + d] = val;
        else            kbuf[(bh * NTOK + n) * DH + d] = val;
      }
    }
    return;
  }
  unsigned short* vt_lds = (unsigned short*)(smem + 32768);
#pragma unroll
  for (int c = 0; c < 8; c++) {
#pragma unroll
    for (int r = 0; r < 4; r++) {
      int nl = w * 16 + 4 * g + r;
      int d = c * 16 + lo;
      int boff = d * 128 + ((nl * 2) ^ ((d & 7) << 4));
      *(unsigned short*)((char*)vt_lds + boff) = f2bf(acc[c][r]);
    }
  }
  __syncthreads();
  int t = threadIdx.x;
  int d = t >> 1, half = t & 1;
  int bb = (bx * 64) >> 11;
  int n0 = (bx * 64) & (NTOK - 1);
  size_t bh = (size_t)(bb * NH + by);
  unsigned short* dst = vtb + (bh * DH + d) * NTOK + n0 + half * 32;
  const char* srcb = (const char*)vt_lds + d * 128;
#pragma unroll
  for (int s = 0; s < 4; s++) {
    int lb = (half * 64 + s * 16) ^ ((d & 7) << 4);
    *(u16x8*)(dst + s * 8) = *(const u16x8*)(srcb + lb);
  }
}

// ======== split-K flash attention (primary path): 1024 blocks, 4 blocks/CU ========
// Block = (bh, qc, split): 128 q-rows, keys [split*1024, +1024), KVBLK=32.
// LDS 32KB: K 2x8KB (rows 256B, swz (r&7)<<4), V 2x8KB (rows 64B, swz (d&3)<<4).
// Writes unnormalized partials o (f32), l, m; k_comb merges the two splits.
__device__ __forceinline__ void stageK32(const char* Kg, char* kl, int w, int lane) {
#pragma unroll
  for (int s = 0; s < 2; s++) {
    int a = s * 4096 + w * 1024 + lane * 16;
    int r = a >> 8;
    int cb = (a & 255) ^ ((r & 7) << 4);
    GLL(Kg + r * 256 + cb, kl + s * 4096 + w * 1024);
  }
}
__device__ __forceinline__ void stageV32(const char* Vg, char* vl, int w, int lane) {
#pragma unroll
  for (int s = 0; s < 2; s++) {
    int a = s * 4096 + w * 1024 + lane * 16;
    int r = a >> 6;
    int cb = (a & 63) ^ ((r & 3) << 4);
    GLL(Vg + (size_t)r * (NTOK * 2) + cb, vl + s * 4096 + w * 1024);
  }
}

__global__ __launch_bounds__(256, 4) void k_attn32s(
    const unsigned short* __restrict__ qb, const unsigned short* __restrict__ kbuf,
    const unsigned short* __restrict__ vtb, const unsigned int* __restrict__ mbits,
    float* __restrict__ opart, float* __restrict__ lpart, float* __restrict__ mpart) {
  __shared__ char smem[32768];   // K: 0,8192 ; V: 16384,24576
  int bid = blockIdx.x;          // [qc:4][split:1][mid2:2][low3:3]
  int low3 = bid & 7, mid2 = (bid >> 3) & 3, split = (bid >> 5) & 1, qc = bid >> 6;
  int b = low3 >> 1, h = ((low3 & 1) << 2) | mid2;
  int bh = b * 8 + h;
  int lane = threadIdx.x & 63, w = threadIdx.x >> 6;
  int ql = lane & 31, hi = lane >> 5;
  int q0 = qc * 128 + w * 32;
  const char* Kg = (const char*)(kbuf + (size_t)bh * NTOK * DH) + (size_t)split * 1024 * 256;
  const char* Vg = (const char*)(vtb + (size_t)bh * NTOK * DH) + (size_t)split * 2048;
  int xk = (ql & 7) << 4;
  int xv = (ql & 3) << 4;

  bf16x8 qf[8];
  {
    const unsigned short* qrow = qb + (size_t)bh * NTOK * DH + (size_t)(q0 + ql) * DH + 8 * hi;
#pragma unroll
    for (int s = 0; s < 8; s++) qf[s] = ldb(qrow + 16 * s);
  }
  const unsigned int* mrow = mbits + (size_t)b * (NTOK * NTOK / 32)
                           + (size_t)(q0 + ql) * (NTOK / 32) + split * 32;
  char* kl = smem;
  char* vl = smem + 16384;
  stageK32(Kg, kl, w, lane);
  stageV32(Vg, vl, w, lane);
  __syncthreads();

  f32x16 o0 = {}, o1 = {}, o2 = {}, o3 = {};
  float m = 0.0f, l = 0.0f;
  for (int kt = 0; kt < 32; kt++) {
    int cur = kt & 1;
    const char* kc = kl + cur * 8192;
    const char* vc = vl + cur * 8192;
    if (kt < 31) {
      stageK32(Kg + (size_t)(kt + 1) * 8192, kl + (1 - cur) * 8192, w, lane);
      stageV32(Vg + (size_t)(kt + 1) * 64, vl + (1 - cur) * 8192, w, lane);
    }
    unsigned int mword = mrow[kt];
    // --- S^T = K.Q^T (8 MFMA), keys kt*32..+32 ---
    f32x16 sT = {};
    const char* kr = kc + ql * 256;
#pragma unroll
    for (int s = 0; s < 8; s++)
      sT = mfma32(ldsb(kr + ((32 * s + 16 * hi) ^ xk)), qf[s], sT);
    // --- masked exp2 softmax (defer-max m, uniform) ---
    unsigned int mw = mword >> (4 * hi);
    float sv[16];
#pragma unroll
    for (int r = 0; r < 16; r++) {
      int cp = (r & 3) + 8 * (r >> 2);
      sv[r] = ((mw >> cp) & 1u) ? sT[r] : -3.0e38f;
    }
    float ps = 0.f;
#pragma unroll
    for (int r = 0; r < 16; r++) { sv[r] = exp2a(sv[r] - m); ps += sv[r]; }
    ps += __shfl_xor(ps, 32, 64);
    l += ps;
    // --- pack bf16 + half-exchange -> PV A-fragments (proven pattern) ---
    unsigned int w8[8], pa[8];
#pragma unroll
    for (int j = 0; j < 8; j++) w8[j] = cvtpk(sv[2 * j], sv[2 * j + 1]);
#pragma unroll
    for (int j = 0; j < 8; j++) pa[j] = __shfl_xor((int)w8[j], 32, 64);
    u32x4 t0, t1;
    if (hi) {
      t0 = u32x4{pa[2], pa[3], w8[2], w8[3]};
      t1 = u32x4{pa[6], pa[7], w8[6], w8[7]};
    } else {
      t0 = u32x4{w8[0], w8[1], pa[0], pa[1]};
      t1 = u32x4{w8[4], w8[5], pa[4], pa[5]};
    }
    bf16x8 fk0 = __builtin_bit_cast(bf16x8, t0);
    bf16x8 fk1 = __builtin_bit_cast(bf16x8, t1);
    // --- PV (8 MFMA) from V tile [128d][32n], rows 64B swz (d&3)<<4 ---
    {
      const char* vr0 = vc + (ql + 0) * 64;
      const char* vr1 = vc + (ql + 32) * 64;
      const char* vr2 = vc + (ql + 64) * 64;
      const char* vr3 = vc + (ql + 96) * 64;
      int c0 = (16 * hi) ^ xv, c1 = (32 + 16 * hi) ^ xv;
      o0 = mfma32(fk0, ldsb(vr0 + c0), o0);
      o1 = mfma32(fk0, ldsb(vr1 + c0), o1);
      o2 = mfma32(fk0, ldsb(vr2 + c0), o2);
      o3 = mfma32(fk0, ldsb(vr3 + c0), o3);
      o0 = mfma32(fk1, ldsb(vr0 + c1), o0);
      o1 = mfma32(fk1, ldsb(vr1 + c1), o1);
      o2 = mfma32(fk1, ldsb(vr2 + c1), o2);
      o3 = mfma32(fk1, ldsb(vr3 + c1), o3);
    }
    if (__any(ps > 65536.0f)) {    // overflow guard AFTER PV: o,l scaled together
      const float c = 1.52587890625e-05f;  // 2^-16
      m += 16.0f; l *= c;
#pragma unroll
      for (int r = 0; r < 16; r++) { o0[r] *= c; o1[r] *= c; o2[r] *= c; o3[r] *= c; }
    }
    __syncthreads();
  }
  // --- store unnormalized partials ---
  size_t prow = (size_t)split * (32 * NTOK) + (size_t)bh * NTOK;
#pragma unroll
  for (int r = 0; r < 16; r++) {
    int q = q0 + (r & 3) + 8 * (r >> 2) + 4 * hi;
    float* op = opart + (prow + q) * 128;
    op[ql]      = o0[r];
    op[32 + ql] = o1[r];
    op[64 + ql] = o2[r];
    op[96 + ql] = o3[r];
  }
  if (hi == 0) {
    lpart[prow + q0 + ql] = l;
    mpart[prow + q0 + ql] = m;
  }
}

// combine the two K-splits: O = sum(o_s*2^(m_s-M)) / sum(l_s*2^(m_s-M))
__global__ __launch_bounds__(256) void k_comb(
    const float* __restrict__ opart, const float* __restrict__ lpart,
    const float* __restrict__ mpart, unsigned short* __restrict__ aout) {
  int idx = blockIdx.x * 256 + threadIdx.x;   // 2,097,152 float4s
  int d4 = idx & 31;
  int row = idx >> 5;                         // bh*2048 + q
  float l0 = lpart[row], l1 = lpart[65536 + row];
  float m0 = mpart[row], m1 = mpart[65536 + row];
  float M = fmaxf(m0, m1);
  float w0 = exp2a(m0 - M), w1 = exp2a(m1 - M);
  float den = l0 * w0 + l1 * w1;
  float inv = den > 0.f ? 1.0f / den : 0.f;
  float4 a = *((const float4*)(opart + (size_t)row * 128) + d4);
  float4 c = *((const float4*)(opart + ((size_t)65536 + row) * 128) + d4);
  ushort4 r;
  r.x = f2bf((a.x * w0 + c.x * w1) * inv);
  r.y = f2bf((a.y * w0 + c.y * w1) * inv);
  r.z = f2bf((a.z * w0 + c.z * w1) * inv);
  r.w = f2bf((a.w * w0 + c.w * w1) * inv);
  int bh = row >> 11, q = row & (NTOK - 1);
  int b = bh >> 3, h = bh & 7;
  *(ushort4*)(aout + ((size_t)(b * NTOK + q) * 1024) + h * 128 + d4 * 4) = r;
}

// ======== fallback attention (round-7/9 kernel, used if ws too small) ========
__device__ __forceinline__ void stageK(const char* Kg, char* kl, int w, int lane) {
#pragma unroll
  for (int s = 0; s < 4; s++) {
    int a = s * 4096 + w * 1024 + lane * 16;
    int r = a >> 8;
    int cb = (a & 255) ^ ((r & 7) << 4);
    GLL(Kg + r * 256 + cb, kl + s * 4096 + w * 1024);
  }
}
__device__ __forceinline__ void stageV(const char* Vg, char* vl, int w, int lane) {
#pragma unroll
  for (int s = 0; s < 4; s++) {
    int a = s * 4096 + w * 1024 + lane * 16;
    int r = a >> 7;
    int cb = (a & 127) ^ ((r & 7) << 4);
    GLL(Vg + (size_t)r * (NTOK * 2) + cb, vl + s * 4096 + w * 1024);
  }
}

#define QKBLK(SC0, SC1, KC)                                                    \
  {                                                                            \
    _Pragma("unroll") for (int r_ = 0; r_ < 16; r_++) { SC0[r_] = 0.f; SC1[r_] = 0.f; } \
    const char* kr0_ = (KC) + ql * 256;                                        \
    const char* kr1_ = (KC) + (32 + ql) * 256;                                 \
    _Pragma("unroll")                                                          \
    for (int s_ = 0; s_ < 8; s_++) {                                           \
      int cb_ = (32 * s_ + 16 * hi) ^ xk;                                      \
      SC0 = mfma32(ldsb(kr0_ + cb_), qf[s_], SC0);                             \
      SC1 = mfma32(ldsb(kr1_ + cb_), qf[s_], SC1);                             \
    }                                                                          \
  }

#define SOFTPACK(SC0, SC1, MMV, PSV, FA0, FA1, FB0, FB1)                       \
  {                                                                            \
    unsigned int mw0_ = (MMV).x >> (4 * hi), mw1_ = (MMV).y >> (4 * hi);       \
    float sv0_[16], sv1_[16];                                                  \
    _Pragma("unroll")                                                          \
    for (int r_ = 0; r_ < 16; r_++) {                                          \
      int cp_ = (r_ & 3) + 8 * (r_ >> 2);                                      \
      sv0_[r_] = ((mw0_ >> cp_) & 1u) ? SC0[r_] : -3.0e38f;                    \
      sv1_[r_] = ((mw1_ >> cp_) & 1u) ? SC1[r_] : -3.0e38f;                    \
    }                                                                          \
    PSV = 0.f;                                                                 \
    _Pragma("unroll")                                                          \
    for (int r_ = 0; r_ < 16; r_++) { sv0_[r_] = exp2a(sv0_[r_] - m); PSV += sv0_[r_]; } \
    _Pragma("unroll")                                                          \
    for (int r_ = 0; r_ < 16; r_++) { sv1_[r_] = exp2a(sv1_[r_] - m); PSV += sv1_[r_]; } \
    unsigned int w8a_[8], w8b_[8], pa_[8], pb_[8];                             \
    _Pragma("unroll")                                                          \
    for (int j_ = 0; j_ < 8; j_++) {                                           \
      w8a_[j_] = cvtpk(sv0_[2 * j_], sv0_[2 * j_ + 1]);                        \
      w8b_[j_] = cvtpk(sv1_[2 * j_], sv1_[2 * j_ + 1]);                        \
    }                                                                          \
    _Pragma("unroll")                                                          \
    for (int j_ = 0; j_ < 8; j_++) {                                           \
      pa_[j_] = __shfl_xor((int)w8a_[j_], 32, 64);                             \
      pb_[j_] = __shfl_xor((int)w8b_[j_], 32, 64);                             \
    }                                                                          \
    u32x4 ta0_, ta1_, tb0_, tb1_;                                              \
    if (hi) {                                                                  \
      ta0_ = u32x4{pa_[2], pa_[3], w8a_[2], w8a_[3]};                          \
      ta1_ = u32x4{pa_[6], pa_[7], w8a_[6], w8a_[7]};                          \
      tb0_ = u32x4{pb_[2], pb_[3], w8b_[2], w8b_[3]};                          \
      tb1_ = u32x4{pb_[6], pb_[7], w8b_[6], w8b_[7]};                          \
    } else {                                                                   \
      ta0_ = u32x4{w8a_[0], w8a_[1], pa_[0], pa_[1]};                          \
      ta1_ = u32x4{w8a_[4], w8a_[5], pa_[4], pa_[5]};                          \
      tb0_ = u32x4{w8b_[0], w8b_[1], pb_[0], pb_[1]};                          \
      tb1_ = u32x4{w8b_[4], w8b_[5], pb_[4], pb_[5]};                          \
    }                                                                          \
    FA0 = __builtin_bit_cast(bf16x8, ta0_);                                    \
    FA1 = __builtin_bit_cast(bf16x8, ta1_);                                    \
    FB0 = __builtin_bit_cast(bf16x8, tb0_);                                    \
    FB1 = __builtin_bit_cast(bf16x8, tb1_);                                    \
  }

#define PVBLK(FA0, FA1, FB0, FB1, VC)                                          \
  {                                                                            \
    const char* vr0_ = (VC) + (ql + 0) * 128;                                  \
    const char* vr1_ = (VC) + (ql + 32) * 128;                                 \
    const char* vr2_ = (VC) + (ql + 64) * 128;                                 \
    const char* vr3_ = (VC) + (ql + 96) * 128;                                 \
    int c0_ = (16 * hi) ^ xk, c1_ = (32 + 16 * hi) ^ xk;                       \
    int c2_ = (64 + 16 * hi) ^ xk, c3_ = (96 + 16 * hi) ^ xk;                  \
    o0 = mfma32(FA0, ldsb(vr0_ + c0_), o0);                                    \
    o1 = mfma32(FA0, ldsb(vr1_ + c0_), o1);                                    \
    o2 = mfma32(FA0, ldsb(vr2_ + c0_), o2);                                    \
    o3 = mfma32(FA0, ldsb(vr3_ + c0_), o3);                                    \
    o0 = mfma32(FA1, ldsb(vr0_ + c1_), o0);                                    \
    o1 = mfma32(FA1, ldsb(vr1_ + c1_), o1);                                    \
    o2 = mfma32(FA1, ldsb(vr2_ + c1_), o2);                                    \
    o3 = mfma32(FA1, ldsb(vr3_ + c1_), o3);                                    \
    o0 = mfma32(FB0, ldsb(vr0_ + c2_), o0);                                    \
    o1 = mfma32(FB0, ldsb(vr1_ + c2_), o1);                                    \
    o2 = mfma32(FB0, ldsb(vr2_ + c2_), o2);                                    \
    o3 = mfma32(FB0, ldsb(vr3_ + c2_), o3);                                    \
    o0 = mfma32(FB1, ldsb(vr0_ + c3_), o0);                                    \
    o1 = mfma32(FB1, ldsb(vr1_ + c3_), o1);                                    \
    o2 = mfma32(FB1, ldsb(vr2_ + c3_), o2);                                    \
    o3 = mfma32(FB1, ldsb(vr3_ + c3_), o3);                                    \
  }

#define BIG(PSV)                                                               \
  if (__any((PSV) > 65536.0f)) {                                               \
    const float c_ = 1.52587890625e-05f;                                       \
    m += 16.0f; l *= c_;                                                       \
    _Pragma("unroll")                                                          \
    for (int r_ = 0; r_ < 16; r_++) { o0[r_] *= c_; o1[r_] *= c_; o2[r_] *= c_; o3[r_] *= c_; } \
  }

#define BODY(PI0, PI1, PI2, PI3, PSI, PO0, PO1, PO2, PO3, PSO, MMV)            \
  {                                                                            \
    __builtin_amdgcn_s_setprio(1);                                             \
    QKBLK(sT0, sT1, smem + ko_rd);                                             \
    PVBLK(PI0, PI1, PI2, PI3, smem + vo_pv);                                   \
    __builtin_amdgcn_s_setprio(0);                                             \
    l += PSI;                                                                  \
    BIG(PSI);                                                                  \
    SOFTPACK(sT0, sT1, MMV, PSO, PO0, PO1, PO2, PO3);                          \
  }

#define ROT_V() { int t_ = vo_pv; vo_pv = vo_mid; vo_mid = vo_st; vo_st = t_; }
#define SWAP_K() { int t_ = ko_rd; ko_rd = ko_nx; ko_nx = t_; }

#define TAIL(KT, VT, MMREG, MI)                                                \
  __builtin_amdgcn_s_barrier();                                                \
  stageK(Kbase + (size_t)(KT) * 16384, smem + ko_rd, w, lane);                 \
  stageV(Vbase + (size_t)(VT) * 128, smem + vo_st, w, lane);                   \
  SFENCE();                                                                    \
  MMREG = mrow[MI];                                                            \
  SFENCE();                                                                    \
  SWAP_K();                                                                    \
  ROT_V();

__global__ __launch_bounds__(256, 2) void k_attn64(
    const unsigned short* __restrict__ qb, const unsigned short* __restrict__ kbuf,
    const unsigned short* __restrict__ vtb, const unsigned int* __restrict__ mbits,
    unsigned short* __restrict__ aout) {
  __shared__ char smem[81920];
  int bid = blockIdx.x;
  int low3 = bid & 7, mid2 = (bid >> 3) & 3, qc = bid >> 5;
  int b = low3 >> 1, h = ((low3 & 1) << 2) | mid2;
  int bh = b * 8 + h;
  int lane = threadIdx.x & 63, w = threadIdx.x >> 6;
  int ql = lane & 31, hi = lane >> 5;
  int q0 = qc * 128 + w * 32;
  const char* Kbase = (const char*)(kbuf + (size_t)bh * NTOK * DH);
  const char* Vbase = (const char*)(vtb + (size_t)bh * NTOK * DH);
  int xk = (ql & 7) << 4;

  bf16x8 qf[8];
  {
    const unsigned short* qrow = qb + (size_t)bh * NTOK * DH + (size_t)(q0 + ql) * DH + 8 * hi;
#pragma unroll
    for (int s = 0; s < 8; s++) qf[s] = ldb(qrow + 16 * s);
  }
  const uint2* mrow = (const uint2*)(mbits + (size_t)b * (NTOK * NTOK / 32) + (size_t)(q0 + ql) * (NTOK / 32));
  SFENCE();
  uint2 mmB = mrow[0];
  uint2 mmA = mrow[1];
  SFENCE();
  stageK(Kbase, smem + 0, w, lane);
  stageK(Kbase + 16384, smem + 16384, w, lane);
  stageV(Vbase, smem + 32768, w, lane);
  SFENCE();

  int ko_rd = 0, ko_nx = 16384;
  int vo_pv = 65536, vo_mid = 32768, vo_st = 49152;
  f32x16 o0 = {}, o1 = {}, o2 = {}, o3 = {};
  f32x16 sT0, sT1;
  bf16x8 pE0, pE1, pE2, pE3, pO0, pO1, pO2, pO3;
  float psE = 0.f, psO = 0.f;
  float m = 0.0f, l = 0.0f;

  WAITVM(8); __builtin_amdgcn_s_barrier();
  QKBLK(sT0, sT1, smem + ko_rd);
  SOFTPACK(sT0, sT1, mmB, psE, pE0, pE1, pE2, pE3);
  TAIL(2, 1, mmB, 2);
  for (int tt = 1; tt <= 27; tt += 2) {
    WAITVM(9); __builtin_amdgcn_s_barrier();
    BODY(pE0, pE1, pE2, pE3, psE, pO0, pO1, pO2, pO3, psO, mmA);
    TAIL(tt + 2, tt + 1, mmA, tt + 2);
    WAITVM(9); __builtin_amdgcn_s_barrier();
    BODY(pO0, pO1, pO2, pO3, psO, pE0, pE1, pE2, pE3, psE, mmB);
    TAIL(tt + 3, tt + 2, mmB, tt + 3);
  }
  WAITVM(9); __builtin_amdgcn_s_barrier();
  BODY(pE0, pE1, pE2, pE3, psE, pO0, pO1, pO2, pO3, psO, mmA);
  TAIL(31, 30, mmA, 31);
  WAITVM(9); __builtin_amdgcn_s_barrier();
  BODY(pO0, pO1, pO2, pO3, psO, pE0, pE1, pE2, pE3, psE, mmB);
  __builtin_amdgcn_s_barrier();
  stageV(Vbase + (size_t)31 * 128, smem + vo_st, w, lane);
  SFENCE();
  SWAP_K();
  ROT_V();
  WAITVM(4); __builtin_amdgcn_s_barrier();
  BODY(pE0, pE1, pE2, pE3, psE, pO0, pO1, pO2, pO3, psO, mmA);
  ROT_V();
  WAITVM(0); __builtin_amdgcn_s_barrier();
  PVBLK(pO0, pO1, pO2, pO3, smem + vo_pv);
  l += psO;
  float lj = l + __shfl_xor(l, 32, 64);
  float linv = lj > 0.f ? 1.0f / lj : 0.0f;
  float li[16];
#pragma unroll
  for (int r = 0; r < 16; r++) {
    int qr = (r & 3) + 8 * (r >> 2) + 4 * hi;
    li[r] = __shfl(linv, qr, 64);
  }
  unsigned short* obase = aout + (size_t)b * NTOK * (NH * DH) + (size_t)h * DH + ql;
#pragma unroll
  for (int r = 0; r < 16; r++) {
    int qn = q0 + (r & 3) + 8 * (r >> 2) + 4 * hi;
    unsigned short* op = obase + (size_t)qn * (NH * DH);
    op[0]  = f2bf(o0[r] * li[r]);
    op[32] = f2bf(o1[r] * li[r]);
    op[64] = f2bf(o2[r] * li[r]);
    op[96] = f2bf(o3[r] * li[r]);
  }
}

// ---- out-proj (K=1024, K-split over 4 waves) + bias + residual + LN + SiLU + mask ----
__global__ __launch_bounds__(256) void k_gemm3(
    const unsigned short* __restrict__ aout, const unsigned short* __restrict__ wot,
    const float* __restrict__ x, const float* __restrict__ bo,
    const float* __restrict__ gamma, const float* __restrict__ beta,
    const void* __restrict__ nmask, const int* __restrict__ flagp,
    float* __restrict__ out) {
  __shared__ float red[4][16][132];
  int flag = *flagp;
  int lane = threadIdx.x & 63, w = threadIdx.x >> 6;
  int lo = lane & 15, g = lane >> 4;
  int rowb = blockIdx.x * 16;
  int k0 = w * 256;
  f32x4 acc[8] = {};
  const unsigned short* arow = aout + (size_t)(rowb + lo) * 1024 + k0 + g * 8;
#pragma unroll
  for (int ks = 0; ks < 8; ks++) {
    bf16x8 af = ldb(arow + 32 * ks);
#pragma unroll
    for (int t = 0; t < 8; t++) {
      bf16x8 bf = ldb(wot + (size_t)(t * 16 + lo) * 1024 + k0 + g * 8 + 32 * ks);
      acc[t] = mfma16(af, bf, acc[t]);
    }
  }
#pragma unroll
  for (int t = 0; t < 8; t++)
#pragma unroll
    for (int r = 0; r < 4; r++) red[w][4 * g + r][t * 16 + lo] = acc[t][r];
  __syncthreads();
  int row = threadIdx.x >> 4, cg = threadIdx.x & 15;
  float y[8];
#pragma unroll
  for (int j = 0; j < 8; j++) {
    int col = cg * 8 + j;
    y[j] = red[0][row][col] + red[1][row][col] + red[2][row][col] + red[3][row][col]
         + bo[col] + x[(size_t)(rowb + row) * 128 + col];
  }
  float s = 0.f;
#pragma unroll
  for (int j = 0; j < 8; j++) s += y[j];
  s += __shfl_xor(s, 1, 64); s += __shfl_xor(s, 2, 64);
  s += __shfl_xor(s, 4, 64); s += __shfl_xor(s, 8, 64);
  float mu = s * 0.0078125f;
  float vs = 0.f;
#pragma unroll
  for (int j = 0; j < 8; j++) { float d = y[j] - mu; vs += d * d; }
  vs += __shfl_xor(vs, 1, 64); vs += __shfl_xor(vs, 2, 64);
  vs += __shfl_xor(vs, 4, 64); vs += __shfl_xor(vs, 8, 64);
  float rstd = rsqrtf(vs * 0.0078125f + 1e-5f);
  float nm = mask_at(nmask, flag, rowb + row) ? 1.0f : 0.0f;
  float ov[8];
#pragma unroll
  for (int j = 0; j < 8; j++) {
    int col = cg * 8 + j;
    float z = (y[j] - mu) * rstd * gamma[col] + beta[col];
    z = z / (1.0f + __expf(-z));
    ov[j] = z * nm;
  }
  float* op = out + (size_t)(rowb + row) * 128 + cg * 8;
  *(float4*)op = float4{ov[0], ov[1], ov[2], ov[3]};
  *(float4*)(op + 4) = float4{ov[4], ov[5], ov[6], ov[7]};
}

extern "C" void kernel_launch(void* const* d_in, const int* in_sizes, int n_in,
                              void* d_out, int out_size, void* d_ws, size_t ws_size,
                              hipStream_t stream) {
  (void)in_sizes; (void)n_in; (void)out_size;
  const float* x = (const float*)d_in[0];
  const void* amask = d_in[1];
  const void* nmask = d_in[2];
  const float* Wq = (const float*)d_in[3];
  const float* Wk = (const float*)d_in[4];
  const float* Wv = (const float*)d_in[5];
  const float* Wo = (const float*)d_in[6];
  const float* bo = (const float*)d_in[7];
  const float* gamma = (const float*)d_in[8];
  const float* beta = (const float*)d_in[9];
  float* out = (float*)d_out;
  char* ws = (char*)d_ws;

  constexpr size_t OFF_FLAG = 0;
  constexpr size_t OFF_XB   = 256;
  constexpr size_t OFF_WQT  = OFF_XB  + (size_t)8192 * 128 * 2;
  constexpr size_t OFF_WKT  = OFF_WQT + (size_t)1024 * 128 * 2;
  constexpr size_t OFF_WVT  = OFF_WKT + (size_t)1024 * 128 * 2;
  constexpr size_t OFF_WOT  = OFF_WVT + (size_t)1024 * 128 * 2;
  constexpr size_t OFF_BITS = OFF_WOT + (size_t)1024 * 128 * 2;
  constexpr size_t OFF_QB   = OFF_BITS + (size_t)NB * NTOK * NTOK / 8;
  constexpr size_t OFF_KB   = OFF_QB  + (size_t)NB * NH * NTOK * DH * 2;
  constexpr size_t OFF_VTB  = OFF_KB  + (size_t)NB * NH * NTOK * DH * 2;
  constexpr size_t OFF_AO   = OFF_VTB + (size_t)NB * NH * NTOK * DH * 2;
  constexpr size_t TOTAL    = OFF_AO  + (size_t)NB * NTOK * NH * DH * 2;
  // split-K additions
  constexpr size_t OFF_OP   = TOTAL;
  constexpr size_t OFF_LP   = OFF_OP + (size_t)2 * 32 * NTOK * 128 * 4;   // 64MB
  constexpr size_t OFF_MP   = OFF_LP + (size_t)2 * 32 * NTOK * 4;
  constexpr size_t TOTAL2   = OFF_MP + (size_t)2 * 32 * NTOK * 4;
  if (ws_size < TOTAL) return;
  bool use_split = ws_size >= TOTAL2;

  int* flag = (int*)(ws + OFF_FLAG);
  unsigned short* xb  = (unsigned short*)(ws + OFF_XB);
  unsigned short* wqt = (unsigned short*)(ws + OFF_WQT);
  unsigned short* wkt = (unsigned short*)(ws + OFF_WKT);
  unsigned short* wvt = (unsigned short*)(ws + OFF_WVT);
  unsigned short* wot = (unsigned short*)(ws + OFF_WOT);
  unsigned int* bits  = (unsigned int*)(ws + OFF_BITS);
  unsigned short* qb  = (unsigned short*)(ws + OFF_QB);
  unsigned short* kbf = (unsigned short*)(ws + OFF_KB);
  unsigned short* vtb = (unsigned short*)(ws + OFF_VTB);
  unsigned short* ao  = (unsigned short*)(ws + OFF_AO);
  float* opart = (float*)(ws + OFF_OP);
  float* lpart = (float*)(ws + OFF_LP);
  float* mpart = (float*)(ws + OFF_MP);

  k_prep<<<641, 256, 0, stream>>>(x, Wq, Wk, Wv, Wo, (const unsigned int*)amask,
                                  xb, wqt, wkt, wvt, wot, flag);
  k_qkv_pack<<<5120, 256, 0, stream>>>(xb, wqt, wkt, wvt, qb, kbf, vtb,
                                       amask, flag, bits);
  if (use_split) {
    k_attn32s<<<1024, 256, 0, stream>>>(qb, kbf, vtb, bits, opart, lpart, mpart);
    k_comb<<<8192, 256, 0, stream>>>(opart, lpart, mpart, ao);
  } else {
    k_attn64<<<512, 256, 0, stream>>>(qb, kbf, vtb, bits, ao);
  }
  k_gemm3<<<512, 256, 0, stream>>>(ao, wot, x, bo, gamma, beta, nmask, flag, out);
}

// Round 11
// 137.018 us; speedup vs baseline: 1.5833x; 1.5833x over previous
//
#include <hip/hip_runtime.h>

#define NTOK 2048
#define NB 4
#define NH 8
#define DH 128

typedef __bf16 bf16x8 __attribute__((ext_vector_type(8)));
typedef unsigned short u16x8 __attribute__((ext_vector_type(8)));
typedef float f32x4 __attribute__((ext_vector_type(4)));
typedef float f32x16 __attribute__((ext_vector_type(16)));
typedef unsigned int u32x4 __attribute__((ext_vector_type(4)));

__device__ __forceinline__ f32x4 mfma16(bf16x8 a, bf16x8 b, f32x4 c) {
  return __builtin_amdgcn_mfma_f32_16x16x32_bf16(a, b, c, 0, 0, 0);
}
__device__ __forceinline__ f32x16 mfma32(bf16x8 a, bf16x8 b, f32x16 c) {
  return __builtin_amdgcn_mfma_f32_32x32x16_bf16(a, b, c, 0, 0, 0);
}
__device__ __forceinline__ bf16x8 ldb(const unsigned short* p) {
  return __builtin_bit_cast(bf16x8, *(const u16x8*)p);
}
__device__ __forceinline__ bf16x8 ldsb(const char* p) {
  return __builtin_bit_cast(bf16x8, *(const u16x8*)p);
}
__device__ __forceinline__ unsigned short f2bf(float f) {
  unsigned int u = __builtin_bit_cast(unsigned int, f);
  u += 0x7fffu + ((u >> 16) & 1u);
  return (unsigned short)(u >> 16);
}
__device__ __forceinline__ unsigned int cvtpk(float lo, float hi) {
  unsigned int r;
  asm("v_cvt_pk_bf16_f32 %0, %1, %2" : "=v"(r) : "v"(lo), "v"(hi));
  return r;
}
#if __has_builtin(__builtin_amdgcn_exp2f)
__device__ __forceinline__ float exp2a(float x) { return __builtin_amdgcn_exp2f(x); }
#else
__device__ __forceinline__ float exp2a(float x) { return __expf(x * 0.6931471805599453f); }
#endif
// async global->LDS, 16B per lane; LDS dest = wave-uniform base + lane*16
#define GLL(gsrc, ldst) __builtin_amdgcn_global_load_lds(                      \
    (const __attribute__((address_space(1))) void*)(gsrc),                     \
    (__attribute__((address_space(3))) void*)(ldst), 16, 0, 0)
#define WAITVM_(N) asm volatile("s_waitcnt vmcnt(" #N ")" ::: "memory")
#define WAITVM(N) WAITVM_(N)
#define SFENCE() asm volatile("" ::: "memory")

// flag: 0 = int32, 1 = uint8, 2 = float32 (int-compare works for 0/1.0f too)
__device__ __forceinline__ bool mask_at(const void* p, int flag, int idx) {
  if (flag == 1) return ((const unsigned char*)p)[idx] != 0;
  return ((const int*)p)[idx] != 0;
}

// ---- prep: detect mask dtype + cvt x to bf16 + LDS-tiled weight transpose ----
__global__ __launch_bounds__(256) void k_prep(
    const float* __restrict__ x, const float* __restrict__ Wq,
    const float* __restrict__ Wk, const float* __restrict__ Wv,
    const float* __restrict__ Wo, const unsigned int* __restrict__ amdw,
    unsigned short* __restrict__ xb, unsigned short* __restrict__ wqt,
    unsigned short* __restrict__ wkt, unsigned short* __restrict__ wvt,
    unsigned short* __restrict__ wot, int* __restrict__ flag) {
  int bid = blockIdx.x, tid = threadIdx.x;
  if (bid == 0) {
    __shared__ int su8, sf32;
    if (tid == 0) { su8 = 0; sf32 = 0; }
    __syncthreads();
    const uint4* dw4 = (const uint4*)amdw;
    int lu8 = 0, lf32 = 0;
#pragma unroll
    for (int j = 0; j < 16; j++) {
      uint4 q = dw4[tid + j * 256];
      unsigned int vv[4] = {q.x, q.y, q.z, q.w};
#pragma unroll
      for (int e = 0; e < 4; e++) {
        unsigned int v = vv[e];
        if (v == 0x3f800000u) lf32 = 1;
        else if (v != 0u && v != 1u) lu8 = 1;
      }
    }
    if (lu8) atomicOr(&su8, 1);
    if (lf32) atomicOr(&sf32, 1);
    __syncthreads();
    if (tid == 0) *flag = sf32 ? 2 : (su8 ? 1 : 0);
    return;
  }
  if (bid < 513) {
    int base = (bid - 1) * 2048 + tid * 8;
    const float4* xf = (const float4*)(x + base);
    float4 a = xf[0], b = xf[1];
    u16x8 o;
    o[0] = f2bf(a.x); o[1] = f2bf(a.y); o[2] = f2bf(a.z); o[3] = f2bf(a.w);
    o[4] = f2bf(b.x); o[5] = f2bf(b.y); o[6] = f2bf(b.z); o[7] = f2bf(b.w);
    *(u16x8*)(xb + base) = o;
    return;
  }
  __shared__ float tile[64][65];
  int tb = bid - 513;
  int msel = tb >> 5, tt = tb & 31;
  const float* w; unsigned short* wt; int R, C;
  if (msel == 0)      { w = Wq; wt = wqt; R = 128;  C = 1024; }
  else if (msel == 1) { w = Wk; wt = wkt; R = 128;  C = 1024; }
  else if (msel == 2) { w = Wv; wt = wvt; R = 128;  C = 1024; }
  else                { w = Wo; wt = wot; R = 1024; C = 128; }
  int nrt = R >> 6;
  int rt = (tt % nrt) << 6, ct = (tt / nrt) << 6;
  {
    int cl = tid & 63, rg = tid >> 6;
#pragma unroll
    for (int j = 0; j < 16; j++) {
      int row = rg * 16 + j;
      tile[row][cl] = w[(size_t)(rt + row) * C + ct + cl];
    }
  }
  __syncthreads();
  {
    int rl = tid & 63, cg = tid >> 6;
#pragma unroll
    for (int j = 0; j < 16; j++) {
      int col = cg * 16 + j;
      wt[(size_t)(ct + col) * R + rt + rl] = f2bf(tile[rl][col]);
    }
  }
}

// ---- fused QKV projection (LDS-staged weights) + mask bit-pack (word/thread) ----
__global__ __launch_bounds__(256) void k_qkv_pack(
    const unsigned short* __restrict__ xb, const unsigned short* __restrict__ wqt,
    const unsigned short* __restrict__ wkt, const unsigned short* __restrict__ wvt,
    unsigned short* __restrict__ qb, unsigned short* __restrict__ kbuf,
    unsigned short* __restrict__ vtb, const void* __restrict__ am,
    const int* __restrict__ flagp, unsigned int* __restrict__ bits) {
  __shared__ char smem[49152];
  int bid = blockIdx.x;
  int lane = threadIdx.x & 63, w = threadIdx.x >> 6;
  if (bid >= 3072) {
    int flag = *flagp;
    size_t ebase = (size_t)(bid - 3072) * 8192 + (size_t)threadIdx.x * 32;
    unsigned int word = 0;
    if (flag == 1) {
      const uint4* p4 = (const uint4*)((const unsigned char*)am + ebase);
      uint4 q0 = p4[0], q1 = p4[1];
      unsigned int dw[8] = {q0.x, q0.y, q0.z, q0.w, q1.x, q1.y, q1.z, q1.w};
#pragma unroll
      for (int d = 0; d < 8; d++) {
        unsigned int v = dw[d];
        if (v & 0x000000FFu) word |= 1u << (d * 4 + 0);
        if (v & 0x0000FF00u) word |= 1u << (d * 4 + 1);
        if (v & 0x00FF0000u) word |= 1u << (d * 4 + 2);
        if (v & 0xFF000000u) word |= 1u << (d * 4 + 3);
      }
    } else {
      const uint4* p4 = (const uint4*)((const int*)am + ebase);
#pragma unroll
      for (int k = 0; k < 8; k++) {
        uint4 q = p4[k];
        if (q.x) word |= 1u << (k * 4 + 0);
        if (q.y) word |= 1u << (k * 4 + 1);
        if (q.z) word |= 1u << (k * 4 + 2);
        if (q.w) word |= 1u << (k * 4 + 3);
      }
    }
    bits[ebase >> 5] = word;
    return;
  }
  int which = bid >> 10;
  int rem = bid & 1023;
  int bx = rem & 127, by = rem >> 7;
  const unsigned short* wt = which == 0 ? wqt : (which == 1 ? wkt : wvt);
  int lo = lane & 15, g = lane >> 4;
  int rbase = bx * 64 + w * 16;
  int colb = by * 128;
  char* wl = smem;
  {
    const char* Wg = (const char*)(wt + (size_t)colb * 128);
#pragma unroll
    for (int s = 0; s < 8; s++) {
      int a = s * 4096 + w * 1024 + lane * 16;
      int r = a >> 8;
      int cb = (a & 255) ^ ((r & 7) << 4);
      GLL(Wg + r * 256 + cb, wl + s * 4096 + w * 1024);
    }
  }
  bf16x8 af[4];
  const unsigned short* xrow = xb + (size_t)(rbase + lo) * 128 + g * 8;
#pragma unroll
  for (int s = 0; s < 4; s++) af[s] = ldb(xrow + 32 * s);
  __syncthreads();
  f32x4 acc[8] = {};
  int xw = (lo & 7) << 4;
#pragma unroll
  for (int c = 0; c < 8; c++) {
    const char* wrow = wl + (c * 16 + lo) * 256;
#pragma unroll
    for (int s = 0; s < 4; s++)
      acc[c] = mfma16(af[s], ldsb(wrow + ((64 * s + 16 * g) ^ xw)), acc[c]);
  }
  if (which != 2) {
    float sc = (which == 0) ? 0.12751743f : 1.0f;   // log2(e)/sqrt(128)
#pragma unroll
    for (int c = 0; c < 8; c++) {
#pragma unroll
      for (int r = 0; r < 4; r++) {
        int row = rbase + 4 * g + r;
        int col = colb + c * 16 + lo;
        int b = row >> 11, n = row & (NTOK - 1);
        int h = col >> 7, d = col & 127;
        unsigned short val = f2bf(acc[c][r] * sc);
        size_t bh = (size_t)(b * NH + h);
        if (which == 0) qb[(bh * NTOK + n) * DH + d] = val;
        else            kbuf[(bh * NTOK + n) * DH + d] = val;
      }
    }
    return;
  }
  unsigned short* vt_lds = (unsigned short*)(smem + 32768);
#pragma unroll
  for (int c = 0; c < 8; c++) {
#pragma unroll
    for (int r = 0; r < 4; r++) {
      int nl = w * 16 + 4 * g + r;
      int d = c * 16 + lo;
      int boff = d * 128 + ((nl * 2) ^ ((d & 7) << 4));
      *(unsigned short*)((char*)vt_lds + boff) = f2bf(acc[c][r]);
    }
  }
  __syncthreads();
  int t = threadIdx.x;
  int d = t >> 1, half = t & 1;
  int bb = (bx * 64) >> 11;
  int n0 = (bx * 64) & (NTOK - 1);
  size_t bh = (size_t)(bb * NH + by);
  unsigned short* dst = vtb + (bh * DH + d) * NTOK + n0 + half * 32;
  const char* srcb = (const char*)vt_lds + d * 128;
#pragma unroll
  for (int s = 0; s < 4; s++) {
    int lb = (half * 64 + s * 16) ^ ((d & 7) << 4);
    *(u16x8*)(dst + s * 8) = *(const u16x8*)(srcb + lb);
  }
}

// ---- flash attention: P-fragment carried pipeline (QK(t) || PV(t-1)) ----
__device__ __forceinline__ void stageK(const char* Kg, char* kl, int w, int lane) {
#pragma unroll
  for (int s = 0; s < 4; s++) {
    int a = s * 4096 + w * 1024 + lane * 16;
    int r = a >> 8;
    int cb = (a & 255) ^ ((r & 7) << 4);
    GLL(Kg + r * 256 + cb, kl + s * 4096 + w * 1024);
  }
}
__device__ __forceinline__ void stageV(const char* Vg, char* vl, int w, int lane) {
#pragma unroll
  for (int s = 0; s < 4; s++) {
    int a = s * 4096 + w * 1024 + lane * 16;
    int r = a >> 7;
    int cb = (a & 127) ^ ((r & 7) << 4);
    GLL(Vg + (size_t)r * (NTOK * 2) + cb, vl + s * 4096 + w * 1024);
  }
}

#define QKBLK(SC0, SC1, KC)                                                    \
  {                                                                            \
    _Pragma("unroll") for (int r_ = 0; r_ < 16; r_++) { SC0[r_] = 0.f; SC1[r_] = 0.f; } \
    const char* kr0_ = (KC) + ql * 256;                                        \
    const char* kr1_ = (KC) + (32 + ql) * 256;                                 \
    _Pragma("unroll")                                                          \
    for (int s_ = 0; s_ < 8; s_++) {                                           \
      int cb_ = (32 * s_ + 16 * hi) ^ xk;                                      \
      SC0 = mfma32(ldsb(kr0_ + cb_), qf[s_], SC0);                             \
      SC1 = mfma32(ldsb(kr1_ + cb_), qf[s_], SC1);                             \
    }                                                                          \
  }

// mask + exp2 + sum + pack -> A-fragments (round-4-proven exchange)
#define SOFTPACK(SC0, SC1, MMV, PSV, FA0, FA1, FB0, FB1)                       \
  {                                                                            \
    unsigned int mw0_ = (MMV).x >> (4 * hi), mw1_ = (MMV).y >> (4 * hi);       \
    float sv0_[16], sv1_[16];                                                  \
    _Pragma("unroll")                                                          \
    for (int r_ = 0; r_ < 16; r_++) {                                          \
      int cp_ = (r_ & 3) + 8 * (r_ >> 2);                                      \
      sv0_[r_] = ((mw0_ >> cp_) & 1u) ? SC0[r_] : -3.0e38f;                    \
      sv1_[r_] = ((mw1_ >> cp_) & 1u) ? SC1[r_] : -3.0e38f;                    \
    }                                                                          \
    PSV = 0.f;                                                                 \
    _Pragma("unroll")                                                          \
    for (int r_ = 0; r_ < 16; r_++) { sv0_[r_] = exp2a(sv0_[r_] - m); PSV += sv0_[r_]; } \
    _Pragma("unroll")                                                          \
    for (int r_ = 0; r_ < 16; r_++) { sv1_[r_] = exp2a(sv1_[r_] - m); PSV += sv1_[r_]; } \
    unsigned int w8a_[8], w8b_[8], pa_[8], pb_[8];                             \
    _Pragma("unroll")                                                          \
    for (int j_ = 0; j_ < 8; j_++) {                                           \
      w8a_[j_] = cvtpk(sv0_[2 * j_], sv0_[2 * j_ + 1]);                        \
      w8b_[j_] = cvtpk(sv1_[2 * j_], sv1_[2 * j_ + 1]);                        \
    }                                                                          \
    _Pragma("unroll")                                                          \
    for (int j_ = 0; j_ < 8; j_++) {                                           \
      pa_[j_] = __shfl_xor((int)w8a_[j_], 32, 64);                             \
      pb_[j_] = __shfl_xor((int)w8b_[j_], 32, 64);                             \
    }                                                                          \
    u32x4 ta0_, ta1_, tb0_, tb1_;                                              \
    if (hi) {                                                                  \
      ta0_ = u32x4{pa_[2], pa_[3], w8a_[2], w8a_[3]};                          \
      ta1_ = u32x4{pa_[6], pa_[7], w8a_[6], w8a_[7]};                          \
      tb0_ = u32x4{pb_[2], pb_[3], w8b_[2], w8b_[3]};                          \
      tb1_ = u32x4{pb_[6], pb_[7], w8b_[6], w8b_[7]};                          \
    } else {                                                                   \
      ta0_ = u32x4{w8a_[0], w8a_[1], pa_[0], pa_[1]};                          \
      ta1_ = u32x4{w8a_[4], w8a_[5], pa_[4], pa_[5]};                          \
      tb0_ = u32x4{w8b_[0], w8b_[1], pb_[0], pb_[1]};                          \
      tb1_ = u32x4{w8b_[4], w8b_[5], pb_[4], pb_[5]};                          \
    }                                                                          \
    FA0 = __builtin_bit_cast(bf16x8, ta0_);                                    \
    FA1 = __builtin_bit_cast(bf16x8, ta1_);                                    \
    FB0 = __builtin_bit_cast(bf16x8, tb0_);                                    \
    FB1 = __builtin_bit_cast(bf16x8, tb1_);                                    \
  }

#define PVBLK(FA0, FA1, FB0, FB1, VC)                                          \
  {                                                                            \
    const char* vr0_ = (VC) + (ql + 0) * 128;                                  \
    const char* vr1_ = (VC) + (ql + 32) * 128;                                 \
    const char* vr2_ = (VC) + (ql + 64) * 128;                                 \
    const char* vr3_ = (VC) + (ql + 96) * 128;                                 \
    int c0_ = (16 * hi) ^ xk, c1_ = (32 + 16 * hi) ^ xk;                       \
    int c2_ = (64 + 16 * hi) ^ xk, c3_ = (96 + 16 * hi) ^ xk;                  \
    o0 = mfma32(FA0, ldsb(vr0_ + c0_), o0);                                    \
    o1 = mfma32(FA0, ldsb(vr1_ + c0_), o1);                                    \
    o2 = mfma32(FA0, ldsb(vr2_ + c0_), o2);                                    \
    o3 = mfma32(FA0, ldsb(vr3_ + c0_), o3);                                    \
    o0 = mfma32(FA1, ldsb(vr0_ + c1_), o0);                                    \
    o1 = mfma32(FA1, ldsb(vr1_ + c1_), o1);                                    \
    o2 = mfma32(FA1, ldsb(vr2_ + c1_), o2);                                    \
    o3 = mfma32(FA1, ldsb(vr3_ + c1_), o3);                                    \
    o0 = mfma32(FB0, ldsb(vr0_ + c2_), o0);                                    \
    o1 = mfma32(FB0, ldsb(vr1_ + c2_), o1);                                    \
    o2 = mfma32(FB0, ldsb(vr2_ + c2_), o2);                                    \
    o3 = mfma32(FB0, ldsb(vr3_ + c2_), o3);                                    \
    o0 = mfma32(FB1, ldsb(vr0_ + c3_), o0);                                    \
    o1 = mfma32(FB1, ldsb(vr1_ + c3_), o1);                                    \
    o2 = mfma32(FB1, ldsb(vr2_ + c3_), o2);                                    \
    o3 = mfma32(FB1, ldsb(vr3_ + c3_), o3);                                    \
  }

#define BIG(PSV)                                                               \
  if (__any((PSV) > 65536.0f)) {                                               \
    const float c_ = 1.52587890625e-05f;                                       \
    m += 16.0f; l *= c_;                                                       \
    _Pragma("unroll")                                                          \
    for (int r_ = 0; r_ < 16; r_++) { o0[r_] *= c_; o1[r_] *= c_; o2[r_] *= c_; o3[r_] *= c_; } \
  }

// steady body at tile T: QK(T) || PV(T-1); then l/BIG for ps(T-1); then softmax(T)
#define BODY(PI0, PI1, PI2, PI3, PSI, PO0, PO1, PO2, PO3, PSO, MMV)            \
  {                                                                            \
    __builtin_amdgcn_s_setprio(1);                                             \
    QKBLK(sT0, sT1, smem + ko_rd);                                             \
    PVBLK(PI0, PI1, PI2, PI3, smem + vo_pv);                                   \
    __builtin_amdgcn_s_setprio(0);                                             \
    l += PSI;                                                                  \
    BIG(PSI);                                                                  \
    SOFTPACK(sT0, sT1, MMV, PSO, PO0, PO1, PO2, PO3);                          \
  }

#define ROT_V() { int t_ = vo_pv; vo_pv = vo_mid; vo_mid = vo_st; vo_st = t_; }
#define SWAP_K() { int t_ = ko_rd; ko_rd = ko_nx; ko_nx = t_; }

// tail(T): barrier; stage K(T+2), V(T+1); load mrow[T+2] into parity reg; rotate
#define TAIL(KT, VT, MMREG, MI)                                                \
  __builtin_amdgcn_s_barrier();                                                \
  stageK(Kbase + (size_t)(KT) * 16384, smem + ko_rd, w, lane);                 \
  stageV(Vbase + (size_t)(VT) * 128, smem + vo_st, w, lane);                   \
  SFENCE();                                                                    \
  MMREG = mrow[MI];                                                            \
  SFENCE();                                                                    \
  SWAP_K();                                                                    \
  ROT_V();

__global__ __launch_bounds__(256, 2) void k_attn64(
    const unsigned short* __restrict__ qb, const unsigned short* __restrict__ kbuf,
    const unsigned short* __restrict__ vtb, const unsigned int* __restrict__ mbits,
    unsigned short* __restrict__ aout) {
  __shared__ char smem[81920];   // K: 2x16KB @0,16384 ; V: 3x16KB @32768,49152,65536
  int bid = blockIdx.x;
  // XCD swizzle: bid&7 = b*2+(h>>2)
  int low3 = bid & 7, mid2 = (bid >> 3) & 3, qc = bid >> 5;
  int b = low3 >> 1, h = ((low3 & 1) << 2) | mid2;
  int bh = b * 8 + h;
  int lane = threadIdx.x & 63, w = threadIdx.x >> 6;
  int ql = lane & 31, hi = lane >> 5;
  int q0 = qc * 128 + w * 32;
  const char* Kbase = (const char*)(kbuf + (size_t)bh * NTOK * DH);
  const char* Vbase = (const char*)(vtb + (size_t)bh * NTOK * DH);
  int xk = (ql & 7) << 4;

  bf16x8 qf[8];
  {
    const unsigned short* qrow = qb + (size_t)bh * NTOK * DH + (size_t)(q0 + ql) * DH + 8 * hi;
#pragma unroll
    for (int s = 0; s < 8; s++) qf[s] = ldb(qrow + 16 * s);      // 8 VMEM
  }
  const uint2* mrow = (const uint2*)(mbits + (size_t)b * (NTOK * NTOK / 32) + (size_t)(q0 + ql) * (NTOK / 32));
  SFENCE();
  uint2 mmB = mrow[0];                       // +1 (even tiles)
  uint2 mmA = mrow[1];                       // +1 (odd tiles)
  SFENCE();
  stageK(Kbase, smem + 0, w, lane);          // K0 +4
  stageK(Kbase + 16384, smem + 16384, w, lane); // K1 +4
  stageV(Vbase, smem + 32768, w, lane);      // V0 +4 -> slot0
  SFENCE();

  int ko_rd = 0, ko_nx = 16384;
  int vo_pv = 65536, vo_mid = 32768, vo_st = 49152;  // pv=slot(-1), mid=slot0(V0), st=slot1
  f32x16 o0 = {}, o1 = {}, o2 = {}, o3 = {};
  f32x16 sT0, sT1;
  bf16x8 pE0, pE1, pE2, pE3, pO0, pO1, pO2, pO3;
  float psE = 0.f, psO = 0.f;
  float m = 0.0f, l = 0.0f;

  // ---- t=0 (even, mmB): QK + softpack only ----
  WAITVM(8); __builtin_amdgcn_s_barrier();   // drains qf,mm,mm,K0; leaves K1,V0
  QKBLK(sT0, sT1, smem + ko_rd);
  SOFTPACK(sT0, sT1, mmB, psE, pE0, pE1, pE2, pE3);
  TAIL(2, 1, mmB, 2);
  // ---- main t=1..28 (14 unroll-2 pairs) ----
  for (int tt = 1; tt <= 27; tt += 2) {
    WAITVM(9); __builtin_amdgcn_s_barrier(); // drains K(t),V(t-1),mm(t)
    BODY(pE0, pE1, pE2, pE3, psE, pO0, pO1, pO2, pO3, psO, mmA);
    TAIL(tt + 2, tt + 1, mmA, tt + 2);
    WAITVM(9); __builtin_amdgcn_s_barrier();
    BODY(pO0, pO1, pO2, pO3, psO, pE0, pE1, pE2, pE3, psE, mmB);
    TAIL(tt + 3, tt + 2, mmB, tt + 3);
  }
  // ---- t=29 (odd, mmA=mrow[29]) ----
  WAITVM(9); __builtin_amdgcn_s_barrier();
  BODY(pE0, pE1, pE2, pE3, psE, pO0, pO1, pO2, pO3, psO, mmA);
  TAIL(31, 30, mmA, 31);                     // mmA <- mrow[31] for t=31
  // ---- t=30 (even, mmB=mrow[30]); tail stages V31 only ----
  WAITVM(9); __builtin_amdgcn_s_barrier();
  BODY(pO0, pO1, pO2, pO3, psO, pE0, pE1, pE2, pE3, psE, mmB);
  __builtin_amdgcn_s_barrier();
  stageV(Vbase + (size_t)31 * 128, smem + vo_st, w, lane);
  SFENCE();
  SWAP_K();
  ROT_V();
  // ---- t=31 (odd, mmA=mrow[31]) ----
  WAITVM(4); __builtin_amdgcn_s_barrier();   // drains K31,V30,mm31; leaves V31
  BODY(pE0, pE1, pE2, pE3, psE, pO0, pO1, pO2, pO3, psO, mmA);
  ROT_V();                                   // pv -> slot(31)
  // ---- epilogue: PV(31) ----
  WAITVM(0); __builtin_amdgcn_s_barrier();
  PVBLK(pO0, pO1, pO2, pO3, smem + vo_pv);
  l += psO;
  // ---- finalize ----
  float lj = l + __shfl_xor(l, 32, 64);
  float linv = lj > 0.f ? 1.0f / lj : 0.0f;
  float li[16];
#pragma unroll
  for (int r = 0; r < 16; r++) {
    int qr = (r & 3) + 8 * (r >> 2) + 4 * hi;
    li[r] = __shfl(linv, qr, 64);
  }
  unsigned short* obase = aout + (size_t)b * NTOK * (NH * DH) + (size_t)h * DH + ql;
#pragma unroll
  for (int r = 0; r < 16; r++) {
    int qn = q0 + (r & 3) + 8 * (r >> 2) + 4 * hi;
    unsigned short* op = obase + (size_t)qn * (NH * DH);
    op[0]  = f2bf(o0[r] * li[r]);
    op[32] = f2bf(o1[r] * li[r]);
    op[64] = f2bf(o2[r] * li[r]);
    op[96] = f2bf(o3[r] * li[r]);
  }
}

// ---- out-proj (K=1024, K-split over 4 waves) + bias + residual + LN + SiLU + mask ----
__global__ __launch_bounds__(256) void k_gemm3(
    const unsigned short* __restrict__ aout, const unsigned short* __restrict__ wot,
    const float* __restrict__ x, const float* __restrict__ bo,
    const float* __restrict__ gamma, const float* __restrict__ beta,
    const void* __restrict__ nmask, const int* __restrict__ flagp,
    float* __restrict__ out) {
  __shared__ float red[4][16][132];
  int flag = *flagp;
  int lane = threadIdx.x & 63, w = threadIdx.x >> 6;
  int lo = lane & 15, g = lane >> 4;
  int rowb = blockIdx.x * 16;
  int k0 = w * 256;
  f32x4 acc[8] = {};
  const unsigned short* arow = aout + (size_t)(rowb + lo) * 1024 + k0 + g * 8;
#pragma unroll
  for (int ks = 0; ks < 8; ks++) {
    bf16x8 af = ldb(arow + 32 * ks);
#pragma unroll
    for (int t = 0; t < 8; t++) {
      bf16x8 bf = ldb(wot + (size_t)(t * 16 + lo) * 1024 + k0 + g * 8 + 32 * ks);
      acc[t] = mfma16(af, bf, acc[t]);
    }
  }
#pragma unroll
  for (int t = 0; t < 8; t++)
#pragma unroll
    for (int r = 0; r < 4; r++) red[w][4 * g + r][t * 16 + lo] = acc[t][r];
  __syncthreads();
  int row = threadIdx.x >> 4, cg = threadIdx.x & 15;
  float y[8];
#pragma unroll
  for (int j = 0; j < 8; j++) {
    int col = cg * 8 + j;
    y[j] = red[0][row][col] + red[1][row][col] + red[2][row][col] + red[3][row][col]
         + bo[col] + x[(size_t)(rowb + row) * 128 + col];
  }
  float s = 0.f;
#pragma unroll
  for (int j = 0; j < 8; j++) s += y[j];
  s += __shfl_xor(s, 1, 64); s += __shfl_xor(s, 2, 64);
  s += __shfl_xor(s, 4, 64); s += __shfl_xor(s, 8, 64);
  float mu = s * 0.0078125f;
  float vs = 0.f;
#pragma unroll
  for (int j = 0; j < 8; j++) { float d = y[j] - mu; vs += d * d; }
  vs += __shfl_xor(vs, 1, 64); vs += __shfl_xor(vs, 2, 64);
  vs += __shfl_xor(vs, 4, 64); vs += __shfl_xor(vs, 8, 64);
  float rstd = rsqrtf(vs * 0.0078125f + 1e-5f);
  float nm = mask_at(nmask, flag, rowb + row) ? 1.0f : 0.0f;
  float ov[8];
#pragma unroll
  for (int j = 0; j < 8; j++) {
    int col = cg * 8 + j;
    float z = (y[j] - mu) * rstd * gamma[col] + beta[col];
    z = z / (1.0f + __expf(-z));
    ov[j] = z * nm;
  }
  float* op = out + (size_t)(rowb + row) * 128 + cg * 8;
  *(float4*)op = float4{ov[0], ov[1], ov[2], ov[3]};
  *(float4*)(op + 4) = float4{ov[4], ov[5], ov[6], ov[7]};
}

extern "C" void kernel_launch(void* const* d_in, const int* in_sizes, int n_in,
                              void* d_out, int out_size, void* d_ws, size_t ws_size,
                              hipStream_t stream) {
  (void)in_sizes; (void)n_in; (void)out_size;
  const float* x = (const float*)d_in[0];
  const void* amask = d_in[1];
  const void* nmask = d_in[2];
  const float* Wq = (const float*)d_in[3];
  const float* Wk = (const float*)d_in[4];
  const float* Wv = (const float*)d_in[5];
  const float* Wo = (const float*)d_in[6];
  const float* bo = (const float*)d_in[7];
  const float* gamma = (const float*)d_in[8];
  const float* beta = (const float*)d_in[9];
  float* out = (float*)d_out;
  char* ws = (char*)d_ws;

  constexpr size_t OFF_FLAG = 0;
  constexpr size_t OFF_XB   = 256;
  constexpr size_t OFF_WQT  = OFF_XB  + (size_t)8192 * 128 * 2;
  constexpr size_t OFF_WKT  = OFF_WQT + (size_t)1024 * 128 * 2;
  constexpr size_t OFF_WVT  = OFF_WKT + (size_t)1024 * 128 * 2;
  constexpr size_t OFF_WOT  = OFF_WVT + (size_t)1024 * 128 * 2;
  constexpr size_t OFF_BITS = OFF_WOT + (size_t)1024 * 128 * 2;
  constexpr size_t OFF_QB   = OFF_BITS + (size_t)NB * NTOK * NTOK / 8;
  constexpr size_t OFF_KB   = OFF_QB  + (size_t)NB * NH * NTOK * DH * 2;
  constexpr size_t OFF_VTB  = OFF_KB  + (size_t)NB * NH * NTOK * DH * 2;
  constexpr size_t OFF_AO   = OFF_VTB + (size_t)NB * NH * NTOK * DH * 2;
  constexpr size_t TOTAL    = OFF_AO  + (size_t)NB * NTOK * NH * DH * 2;
  if (ws_size < TOTAL) return;

  int* flag = (int*)(ws + OFF_FLAG);
  unsigned short* xb  = (unsigned short*)(ws + OFF_XB);
  unsigned short* wqt = (unsigned short*)(ws + OFF_WQT);
  unsigned short* wkt = (unsigned short*)(ws + OFF_WKT);
  unsigned short* wvt = (unsigned short*)(ws + OFF_WVT);
  unsigned short* wot = (unsigned short*)(ws + OFF_WOT);
  unsigned int* bits  = (unsigned int*)(ws + OFF_BITS);
  unsigned short* qb  = (unsigned short*)(ws + OFF_QB);
  unsigned short* kbf = (unsigned short*)(ws + OFF_KB);
  unsigned short* vtb = (unsigned short*)(ws + OFF_VTB);
  unsigned short* ao  = (unsigned short*)(ws + OFF_AO);

  k_prep<<<641, 256, 0, stream>>>(x, Wq, Wk, Wv, Wo, (const unsigned int*)amask,
                                  xb, wqt, wkt, wvt, wot, flag);
  k_qkv_pack<<<5120, 256, 0, stream>>>(xb, wqt, wkt, wvt, qb, kbf, vtb,
                                       amask, flag, bits);
  k_attn64<<<512, 256, 0, stream>>>(qb, kbf, vtb, bits, ao);
  k_gemm3<<<512, 256, 0, stream>>>(ao, wot, x, bo, gamma, beta, nmask, flag, out);
}